// Round 1
// baseline (714.617 us; speedup 1.0000x reference)
//
#include <hip/hip_runtime.h>

// GCN 2-layer: h = relu(gcn(x,W1,b1)); out = gcn(h,W2,b2)
// gcn factored: out[c] = dis[c] * ( dis[c]*h[c] + sum_{(r,c) in E} dis[r]*h[r] ) + b

__global__ void deg_count(const int* __restrict__ col, float* __restrict__ degf, int E) {
    int e = blockIdx.x * blockDim.x + threadIdx.x;
    if (e < E) atomicAdd(&degf[col[e]], 1.0f);
}

// dis[i] = rsqrt(deg+1); acc1[i*16+k] = dis[i] * (x[i] @ W1)[k]   (self-loop term)
__global__ void dis_init1(const float* __restrict__ x, float* __restrict__ dis,
                          const float* __restrict__ W1, float* __restrict__ acc1, int N) {
    __shared__ float sW[48];
    if (threadIdx.x < 48) sW[threadIdx.x] = W1[threadIdx.x];
    __syncthreads();
    int i = blockIdx.x * blockDim.x + threadIdx.x;
    if (i >= N) return;
    float d = rsqrtf(dis[i] + 1.0f);  // dis[] currently holds edge-only degree
    dis[i] = d;
    float x0 = x[3 * i], x1 = x[3 * i + 1], x2 = x[3 * i + 2];
    float4* out = (float4*)(acc1 + (size_t)i * 16);
#pragma unroll
    for (int q = 0; q < 4; q++) {
        float4 v;
        v.x = d * (x0 * sW[q * 4 + 0] + x1 * sW[16 + q * 4 + 0] + x2 * sW[32 + q * 4 + 0]);
        v.y = d * (x0 * sW[q * 4 + 1] + x1 * sW[16 + q * 4 + 1] + x2 * sW[32 + q * 4 + 1]);
        v.z = d * (x0 * sW[q * 4 + 2] + x1 * sW[16 + q * 4 + 2] + x2 * sW[32 + q * 4 + 2]);
        v.w = d * (x0 * sW[q * 4 + 3] + x1 * sW[16 + q * 4 + 3] + x2 * sW[32 + q * 4 + 3]);
        out[q] = v;
    }
}

// one thread per (edge, k): m = dis[r]*(x[r]@W1)[k]; atomicAdd acc1[c*16+k]
__global__ void agg1(const int* __restrict__ ei, const float* __restrict__ x,
                     const float* __restrict__ dis, const float* __restrict__ W1,
                     float* __restrict__ acc1, int E) {
    __shared__ float sW[48];
    if (threadIdx.x < 48) sW[threadIdx.x] = W1[threadIdx.x];
    __syncthreads();
    int t = blockIdx.x * blockDim.x + threadIdx.x;
    int e = t >> 4, k = t & 15;
    if (e >= E) return;
    int r = ei[e], c = ei[E + e];
    float x0 = x[3 * r], x1 = x[3 * r + 1], x2 = x[3 * r + 2];
    float m = (x0 * sW[k] + x1 * sW[16 + k] + x2 * sW[32 + k]) * dis[r];
    atomicAdd(&acc1[(size_t)c * 16 + k], m);
}

// z = relu(dis*acc1 + b1); hs2 = dis * (z @ W2); acc2 = hs2 (self loop)
__global__ void post1(const float* __restrict__ acc1, const float* __restrict__ dis,
                      const float* __restrict__ b1, const float* __restrict__ W2,
                      float* __restrict__ hs2, float* __restrict__ acc2, int N) {
    __shared__ float sb[16], sw[16];
    if (threadIdx.x < 16) { sb[threadIdx.x] = b1[threadIdx.x]; sw[threadIdx.x] = W2[threadIdx.x]; }
    __syncthreads();
    int i = blockIdx.x * blockDim.x + threadIdx.x;
    if (i >= N) return;
    float d = dis[i];
    const float4* a = (const float4*)(acc1 + (size_t)i * 16);
    float s = 0.f;
#pragma unroll
    for (int q = 0; q < 4; q++) {
        float4 v = a[q];
        float z;
        z = fmaxf(d * v.x + sb[q * 4 + 0], 0.f); s += z * sw[q * 4 + 0];
        z = fmaxf(d * v.y + sb[q * 4 + 1], 0.f); s += z * sw[q * 4 + 1];
        z = fmaxf(d * v.z + sb[q * 4 + 2], 0.f); s += z * sw[q * 4 + 2];
        z = fmaxf(d * v.w + sb[q * 4 + 3], 0.f); s += z * sw[q * 4 + 3];
    }
    float h = d * s;
    hs2[i] = h;
    acc2[i] = h;
}

__global__ void agg2(const int* __restrict__ ei, const float* __restrict__ hs2,
                     float* __restrict__ acc2, int E) {
    int e = blockIdx.x * blockDim.x + threadIdx.x;
    if (e >= E) return;
    int r = ei[e], c = ei[E + e];
    atomicAdd(&acc2[c], hs2[r]);
}

__global__ void finalize(const float* __restrict__ acc2, const float* __restrict__ dis,
                         const float* __restrict__ b2, float* __restrict__ out, int N) {
    int i = blockIdx.x * blockDim.x + threadIdx.x;
    if (i < N) out[i] = dis[i] * acc2[i] + b2[0];
}

extern "C" void kernel_launch(void* const* d_in, const int* in_sizes, int n_in,
                              void* d_out, int out_size, void* d_ws, size_t ws_size,
                              hipStream_t stream) {
    const float* x  = (const float*)d_in[0];
    const int*   ei = (const int*)d_in[1];
    const float* W1 = (const float*)d_in[2];
    const float* b1 = (const float*)d_in[3];
    const float* W2 = (const float*)d_in[4];
    const float* b2 = (const float*)d_in[5];
    float* out = (float*)d_out;

    const int N = in_sizes[0] / 3;
    const int E = in_sizes[1] / 2;

    float* ws   = (float*)d_ws;
    float* dis  = ws;                    // N floats (deg, then dis in-place)
    float* acc1 = ws + (size_t)N;        // N*16 floats
    float* hs2  = ws + (size_t)17 * N;   // N floats
    float* acc2 = ws + (size_t)18 * N;   // N floats

    const int B = 256;
    hipMemsetAsync(dis, 0, (size_t)N * sizeof(float), stream);
    deg_count<<<(E + B - 1) / B, B, 0, stream>>>(ei + E, dis, E);
    dis_init1<<<(N + B - 1) / B, B, 0, stream>>>(x, dis, W1, acc1, N);
    {
        long long t = (long long)E * 16;
        agg1<<<(int)((t + B - 1) / B), B, 0, stream>>>(ei, x, dis, W1, acc1, E);
    }
    post1<<<(N + B - 1) / B, B, 0, stream>>>(acc1, dis, b1, W2, hs2, acc2, N);
    agg2<<<(E + B - 1) / B, B, 0, stream>>>(ei, hs2, acc2, E);
    finalize<<<(N + B - 1) / B, B, 0, stream>>>(acc2, dis, b2, out, N);
}

// Round 2
// 678.511 us; speedup vs baseline: 1.0532x; 1.0532x over previous
//
#include <hip/hip_runtime.h>

// GCN 2-layer, aggregation-before-transform factoring:
//   layer1: out = relu( dis * ((A_norm_agg x)@W1) + b1 ),  A-agg of xs[r]=dis[r]*x[r]
//   layer2: out = dis * (A_agg hs2) + b2,                  hs2[i]=dis[i]*(h1[i]@W2)
// self-loops fused by initializing accumulators with the node's own term.

__global__ void deg_count(const int* __restrict__ col, float* __restrict__ degf, int E) {
    int e = blockIdx.x * blockDim.x + threadIdx.x;
    if (e < E) atomicAdd(&degf[col[e]], 1.0f);
}

// dis = rsqrt(deg+1); xs4[i] = {dis*x0, dis*x1, dis*x2, 0}; accx[i] = xs4[i] (self loop)
__global__ void pass_a(const float* __restrict__ x, const float* __restrict__ deg,
                       float* __restrict__ dis, float4* __restrict__ xs4,
                       float4* __restrict__ accx, int N) {
    int i = blockIdx.x * blockDim.x + threadIdx.x;
    if (i >= N) return;
    float d = rsqrtf(deg[i] + 1.0f);
    dis[i] = d;
    float4 v;
    v.x = d * x[3 * i];
    v.y = d * x[3 * i + 1];
    v.z = d * x[3 * i + 2];
    v.w = 0.f;
    xs4[i] = v;
    accx[i] = v;
}

// 4 threads per edge: accx[c].k += xs4[r].k for k<3
__global__ void agg_x(const int* __restrict__ ei, const float* __restrict__ xs4,
                      float* __restrict__ accx, int E) {
    int t = blockIdx.x * blockDim.x + threadIdx.x;
    int e = t >> 2, k = t & 3;
    if (e >= E) return;
    int r = ei[e], c = ei[E + e];
    float val = xs4[4 * r + k];
    if (k < 3) atomicAdd(&accx[4 * c + k], val);
}

// z[k] = relu(dis*(accx @ W1)[k] + b1[k]); hs2 = dis * (z @ W2); acc2 = hs2 (self loop)
__global__ void post1(const float4* __restrict__ accx, const float* __restrict__ dis,
                      const float* __restrict__ W1, const float* __restrict__ b1,
                      const float* __restrict__ W2,
                      float* __restrict__ hs2, float* __restrict__ acc2, int N) {
    __shared__ float sW[48], sb[16], sw2[16];
    if (threadIdx.x < 48) sW[threadIdx.x] = W1[threadIdx.x];
    if (threadIdx.x < 16) { sb[threadIdx.x] = b1[threadIdx.x]; sw2[threadIdx.x] = W2[threadIdx.x]; }
    __syncthreads();
    int i = blockIdx.x * blockDim.x + threadIdx.x;
    if (i >= N) return;
    float d = dis[i];
    float4 a = accx[i];
    float s = 0.f;
#pragma unroll
    for (int k = 0; k < 16; k++) {
        float z = fmaxf(d * (a.x * sW[k] + a.y * sW[16 + k] + a.z * sW[32 + k]) + sb[k], 0.f);
        s += z * sw2[k];
    }
    float h = d * s;
    hs2[i] = h;
    acc2[i] = h;
}

__global__ void agg2(const int* __restrict__ ei, const float* __restrict__ hs2,
                     float* __restrict__ acc2, int E) {
    int e = blockIdx.x * blockDim.x + threadIdx.x;
    if (e >= E) return;
    int r = ei[e], c = ei[E + e];
    atomicAdd(&acc2[c], hs2[r]);
}

__global__ void finalize(const float* __restrict__ acc2, const float* __restrict__ dis,
                         const float* __restrict__ b2, float* __restrict__ out, int N) {
    int i = blockIdx.x * blockDim.x + threadIdx.x;
    if (i < N) out[i] = dis[i] * acc2[i] + b2[0];
}

extern "C" void kernel_launch(void* const* d_in, const int* in_sizes, int n_in,
                              void* d_out, int out_size, void* d_ws, size_t ws_size,
                              hipStream_t stream) {
    const float* x  = (const float*)d_in[0];
    const int*   ei = (const int*)d_in[1];
    const float* W1 = (const float*)d_in[2];
    const float* b1 = (const float*)d_in[3];
    const float* W2 = (const float*)d_in[4];
    const float* b2 = (const float*)d_in[5];
    float* out = (float*)d_out;

    const int N = in_sizes[0] / 3;
    const int E = in_sizes[1] / 2;

    float* ws   = (float*)d_ws;
    float* deg  = ws;                    // N
    float* dis  = ws + (size_t)N;        // N
    float* xs4  = ws + (size_t)2 * N;    // 4N
    float* accx = ws + (size_t)6 * N;    // 4N
    float* hs2  = ws + (size_t)10 * N;   // N
    float* acc2 = ws + (size_t)11 * N;   // N

    const int B = 256;
    hipMemsetAsync(deg, 0, (size_t)N * sizeof(float), stream);
    deg_count<<<(E + B - 1) / B, B, 0, stream>>>(ei + E, deg, E);
    pass_a<<<(N + B - 1) / B, B, 0, stream>>>(x, deg, dis, (float4*)xs4, (float4*)accx, N);
    {
        long long t = (long long)E * 4;
        agg_x<<<(int)((t + B - 1) / B), B, 0, stream>>>(ei, xs4, accx, E);
    }
    post1<<<(N + B - 1) / B, B, 0, stream>>>((const float4*)accx, dis, W1, b1, W2, hs2, acc2, N);
    agg2<<<(E + B - 1) / B, B, 0, stream>>>(ei, hs2, acc2, E);
    finalize<<<(N + B - 1) / B, B, 0, stream>>>(acc2, dis, b2, out, N);
}